// Round 13
// baseline (127.484 us; speedup 1.0000x reference)
//
#include <hip/hip_runtime.h>
#include <math.h>

// Round 13: R12 (verified) + ONE change: register-prefetch of the Tsep panel.
//   sep's 16 float4 global loads depend only on (g, tid) -> issue them at kernel
//   top, right after the x loads; they complete under the 4 forward FFT stages
//   (barriers are memory fences, so the compiler cannot sink them), and the sep
//   pass consumes pure registers. +64 VGPR live across stages (~124 total,
//   under the 128 cap at 16 waves/CU via __launch_bounds__(1024,2)).
// Everything else identical to round 12 (float4-fused LDS slots, R9 tsep).

#define NFFT 8192
#define NTHR 1024
#define PAD(i) ((i) + ((i) >> 4))
#define LDS_ELEMS (NFFT + (NFFT >> 4))          // 8704 slots
#define TWO_PI 6.28318530717958647692f
#define RSQRT2 0.70710678118654752440f

// ---------------- float2 complex ----------------
__device__ __forceinline__ float2 cadd(float2 a, float2 b){ return make_float2(a.x+b.x, a.y+b.y); }
__device__ __forceinline__ float2 csub(float2 a, float2 b){ return make_float2(a.x-b.x, a.y-b.y); }
__device__ __forceinline__ float2 cmul(float2 a, float2 b){ return make_float2(a.x*b.x - a.y*b.y, a.x*b.y + a.y*b.x); }
__device__ __forceinline__ float2 mulnegi(float2 a){ return make_float2(a.y, -a.x); }
__device__ __forceinline__ float2 mulposi(float2 a){ return make_float2(-a.y, a.x); }
__device__ __forceinline__ float2 mulw81(float2 z){ return make_float2(RSQRT2*(z.x+z.y), RSQRT2*(z.y-z.x)); }  // e^{-i pi/4}
__device__ __forceinline__ float2 mulw83(float2 z){ return make_float2(RSQRT2*(z.y-z.x), -RSQRT2*(z.x+z.y)); } // e^{-i 3pi/4}
__device__ __forceinline__ float2 mulv81(float2 z){ return make_float2(RSQRT2*(z.x-z.y), RSQRT2*(z.x+z.y)); }  // e^{+i pi/4}
__device__ __forceinline__ float2 mulv83(float2 z){ return make_float2(-RSQRT2*(z.x+z.y), RSQRT2*(z.x-z.y)); } // e^{+i 3pi/4}

// ---------------- float4 = two packed complex, shared twiddle ----------------
__device__ __forceinline__ float4 cadd4(float4 a, float4 b){ return make_float4(a.x+b.x,a.y+b.y,a.z+b.z,a.w+b.w); }
__device__ __forceinline__ float4 csub4(float4 a, float4 b){ return make_float4(a.x-b.x,a.y-b.y,a.z-b.z,a.w-b.w); }
__device__ __forceinline__ float4 cmul4(float4 a, float2 w){
    return make_float4(a.x*w.x - a.y*w.y, a.x*w.y + a.y*w.x,
                       a.z*w.x - a.w*w.y, a.z*w.y + a.w*w.x);
}
__device__ __forceinline__ float4 mulnegi4(float4 a){ return make_float4(a.y,-a.x, a.w,-a.z); }
__device__ __forceinline__ float4 mulposi4(float4 a){ return make_float4(-a.y,a.x, -a.w,a.z); }
__device__ __forceinline__ float4 mulw81_4(float4 z){
    return make_float4(RSQRT2*(z.x+z.y), RSQRT2*(z.y-z.x), RSQRT2*(z.z+z.w), RSQRT2*(z.w-z.z)); }
__device__ __forceinline__ float4 mulw83_4(float4 z){
    return make_float4(RSQRT2*(z.y-z.x), -RSQRT2*(z.x+z.y), RSQRT2*(z.w-z.z), -RSQRT2*(z.z+z.w)); }
__device__ __forceinline__ float4 mulv81_4(float4 z){
    return make_float4(RSQRT2*(z.x-z.y), RSQRT2*(z.x+z.y), RSQRT2*(z.z-z.w), RSQRT2*(z.z+z.w)); }
__device__ __forceinline__ float4 mulv83_4(float4 z){
    return make_float4(-RSQRT2*(z.x+z.y), RSQRT2*(z.x-z.y), -RSQRT2*(z.z+z.w), RSQRT2*(z.z-z.w)); }

__device__ __forceinline__ int rev8_12(int u) {   // 4-octal-digit reversal, involution
    return ((u & 7) << 9) | (((u >> 3) & 7) << 6) | (((u >> 6) & 7) << 3) | ((u >> 9) & 7);
}

#define WCHAIN(w1, w2,w3,w4,w5,w6,w7) \
    float2 w2 = cmul(w1,w1), w3 = cmul(w2,w1), w4 = cmul(w2,w2), \
           w5 = cmul(w4,w1), w6 = cmul(w4,w2), w7 = cmul(w4,w3)

// ---------------- float2 radix-8 core (tsep) ----------------
__device__ __forceinline__ void dft8_fwd(float2& a0, float2& a1, float2& a2, float2& a3,
                                         float2& a4, float2& a5, float2& a6, float2& a7) {
    float2 s02 = cadd(a0,a4), d02 = csub(a0,a4), s13 = cadd(a2,a6), d13 = csub(a2,a6);
    float2 E0 = cadd(s02,s13), E2 = csub(s02,s13);
    float2 E1 = cadd(d02, mulnegi(d13)), E3 = csub(d02, mulnegi(d13));
    float2 t02 = cadd(a1,a5), u02 = csub(a1,a5), t13 = cadd(a3,a7), u13 = csub(a3,a7);
    float2 O0 = cadd(t02,t13), O2 = csub(t02,t13);
    float2 O1 = cadd(u02, mulnegi(u13)), O3 = csub(u02, mulnegi(u13));
    float2 W1 = mulw81(O1), W2 = mulnegi(O2), W3 = mulw83(O3);
    a0 = cadd(E0,O0); a4 = csub(E0,O0);
    a1 = cadd(E1,W1); a5 = csub(E1,W1);
    a2 = cadd(E2,W2); a6 = csub(E2,W2);
    a3 = cadd(E3,W3); a7 = csub(E3,W3);
}

// ---------------- float4 radix-8 cores (conv) ----------------
__device__ __forceinline__ void dft8_fwd4(float4& a0, float4& a1, float4& a2, float4& a3,
                                          float4& a4, float4& a5, float4& a6, float4& a7) {
    float4 s02 = cadd4(a0,a4), d02 = csub4(a0,a4), s13 = cadd4(a2,a6), d13 = csub4(a2,a6);
    float4 E0 = cadd4(s02,s13), E2 = csub4(s02,s13);
    float4 E1 = cadd4(d02, mulnegi4(d13)), E3 = csub4(d02, mulnegi4(d13));
    float4 t02 = cadd4(a1,a5), u02 = csub4(a1,a5), t13 = cadd4(a3,a7), u13 = csub4(a3,a7);
    float4 O0 = cadd4(t02,t13), O2 = csub4(t02,t13);
    float4 O1 = cadd4(u02, mulnegi4(u13)), O3 = csub4(u02, mulnegi4(u13));
    float4 W1 = mulw81_4(O1), W2 = mulnegi4(O2), W3 = mulw83_4(O3);
    a0 = cadd4(E0,O0); a4 = csub4(E0,O0);
    a1 = cadd4(E1,W1); a5 = csub4(E1,W1);
    a2 = cadd4(E2,W2); a6 = csub4(E2,W2);
    a3 = cadd4(E3,W3); a7 = csub4(E3,W3);
}

__device__ __forceinline__ void dft8_inv4(float4& a0, float4& a1, float4& a2, float4& a3,
                                          float4& a4, float4& a5, float4& a6, float4& a7) {
    float4 s02 = cadd4(a0,a4), d02 = csub4(a0,a4), s13 = cadd4(a2,a6), d13 = csub4(a2,a6);
    float4 P0 = cadd4(s02,s13), P2 = csub4(s02,s13);
    float4 P1 = cadd4(d02, mulposi4(d13)), P3 = csub4(d02, mulposi4(d13));
    float4 t02 = cadd4(a1,a5), u02 = csub4(a1,a5), t13 = cadd4(a3,a7), u13 = csub4(a3,a7);
    float4 Q0 = cadd4(t02,t13), Q2 = csub4(t02,t13);
    float4 Q1 = cadd4(u02, mulposi4(u13)), Q3 = csub4(u02, mulposi4(u13));
    float4 W1 = mulv81_4(Q1), W2 = mulposi4(Q2), W3 = mulv83_4(Q3);
    a0 = cadd4(P0,Q0); a4 = csub4(P0,Q0);
    a1 = cadd4(P1,W1); a5 = csub4(P1,W1);
    a2 = cadd4(P2,W2); a6 = csub4(P2,W2);
    a3 = cadd4(P3,W3); a7 = csub4(P3,W3);
}

template<int LQ>
__device__ __forceinline__ void fwd_stage4(float4* __restrict__ S, int tid) {
    const int q = 1 << LQ;
    const int m = tid & (q - 1);
    const int B = ((tid >> LQ) << (LQ + 3)) + m;
    const int i0=PAD(B),i1=PAD(B+q),i2=PAD(B+2*q),i3=PAD(B+3*q),
              i4=PAD(B+4*q),i5=PAD(B+5*q),i6=PAD(B+6*q),i7=PAD(B+7*q);
    float sn, cs;
    __sincosf(-TWO_PI * (float)m / (float)(q << 3), &sn, &cs);
    float2 w1 = make_float2(cs, sn);
    WCHAIN(w1, w2,w3,w4,w5,w6,w7);
    float4 a0=S[i0],a1=S[i1],a2=S[i2],a3=S[i3],a4=S[i4],a5=S[i5],a6=S[i6],a7=S[i7];
    dft8_fwd4(a0,a1,a2,a3,a4,a5,a6,a7);
    S[i0]=a0;            S[i1]=cmul4(a1,w1); S[i2]=cmul4(a2,w2); S[i3]=cmul4(a3,w3);
    S[i4]=cmul4(a4,w4);  S[i5]=cmul4(a5,w5); S[i6]=cmul4(a6,w6); S[i7]=cmul4(a7,w7);
}

template<int LQ>
__device__ __forceinline__ void inv_stage4(float4* __restrict__ S, int tid) {
    const int q = 1 << LQ;
    const int m = tid & (q - 1);
    const int B = ((tid >> LQ) << (LQ + 3)) + m;
    const int i0=PAD(B),i1=PAD(B+q),i2=PAD(B+2*q),i3=PAD(B+3*q),
              i4=PAD(B+4*q),i5=PAD(B+5*q),i6=PAD(B+6*q),i7=PAD(B+7*q);
    float sn, cs;
    __sincosf(TWO_PI * (float)m / (float)(q << 3), &sn, &cs);
    float2 w1 = make_float2(cs, sn);
    WCHAIN(w1, w2,w3,w4,w5,w6,w7);
    float4 a0 = S[i0];
    float4 a1=cmul4(S[i1],w1), a2=cmul4(S[i2],w2), a3=cmul4(S[i3],w3), a4=cmul4(S[i4],w4),
           a5=cmul4(S[i5],w5), a6=cmul4(S[i6],w6), a7=cmul4(S[i7],w7);
    dft8_inv4(a0,a1,a2,a3,a4,a5,a6,a7);
    S[i0]=a0; S[i1]=a1; S[i2]=a2; S[i3]=a3; S[i4]=a4; S[i5]=a5; S[i6]=a6; S[i7]=a7;
}

// x stage 1 (L=8192, inputs 4..7 zero), both pairs fused
__device__ __forceinline__ void xstage1_4(float4 a0, float4 a1, float4 a2, float4 a3,
    float4* __restrict__ S, int tid,
    float2 w1,float2 w2,float2 w3,float2 w4,float2 w5,float2 w6,float2 w7) {
    float4 s02 = cadd4(a0,a2), d02 = csub4(a0,a2), s13 = cadd4(a1,a3), d13 = csub4(a1,a3);
    float4 F0 = cadd4(s02,s13), F2 = csub4(s02,s13);
    float4 F1 = cadd4(d02, mulnegi4(d13)), F3 = csub4(d02, mulnegi4(d13));
    float4 g1 = mulw81_4(a1), g2 = mulnegi4(a2), g3 = mulw83_4(a3);
    float4 gs02 = cadd4(a0,g2), gd02 = csub4(a0,g2), gs13 = cadd4(g1,g3), gd13 = csub4(g1,g3);
    float4 G0 = cadd4(gs02,gs13), G2 = csub4(gs02,gs13);
    float4 G1 = cadd4(gd02, mulnegi4(gd13)), G3 = csub4(gd02, mulnegi4(gd13));
    S[PAD(tid)]        = F0;
    S[PAD(tid + 1024)] = cmul4(G0, w1);
    S[PAD(tid + 2048)] = cmul4(F1, w2);
    S[PAD(tid + 3072)] = cmul4(G1, w3);
    S[PAD(tid + 4096)] = cmul4(F2, w4);
    S[PAD(tid + 5120)] = cmul4(G2, w5);
    S[PAD(tid + 6144)] = cmul4(F3, w6);
    S[PAD(tid + 7168)] = cmul4(G3, w7);
}

// final inverse stage (L=8192): time outputs j=0..3 only, both pairs fused
__device__ __forceinline__ void inv_final4(const float4* __restrict__ S, int tid,
    float2 w1,float2 w2,float2 w3,float2 w4,float2 w5,float2 w6,float2 w7,
    float4& r0, float4& r1, float4& r2, float4& r3) {
    float4 z0 = S[PAD(tid)];
    float4 z1 = cmul4(S[PAD(tid + 1024)], w1);
    float4 z2 = cmul4(S[PAD(tid + 2048)], w2);
    float4 z3 = cmul4(S[PAD(tid + 3072)], w3);
    float4 z4 = cmul4(S[PAD(tid + 4096)], w4);
    float4 z5 = cmul4(S[PAD(tid + 5120)], w5);
    float4 z6 = cmul4(S[PAD(tid + 6144)], w6);
    float4 z7 = cmul4(S[PAD(tid + 7168)], w7);
    float4 s02 = cadd4(z0,z4), d02 = csub4(z0,z4), s13 = cadd4(z2,z6), d13 = csub4(z2,z6);
    float4 P0 = cadd4(s02,s13), P2 = csub4(s02,s13);
    float4 P1 = cadd4(d02, mulposi4(d13)), P3 = csub4(d02, mulposi4(d13));
    float4 t02 = cadd4(z1,z5), u02 = csub4(z1,z5), t13 = cadd4(z3,z7), u13 = csub4(z3,z7);
    float4 Q0 = cadd4(t02,t13), Q2 = csub4(t02,t13);
    float4 Q1 = cadd4(u02, mulposi4(u13)), Q3 = csub4(u02, mulposi4(u13));
    r0 = cadd4(P0, Q0);
    r1 = cadd4(P1, mulv81_4(Q1));
    r2 = cadd4(P2, mulposi4(Q2));
    r3 = cadd4(P3, mulv83_4(Q3));
}

// Q = Xd*Td + i*Xe*Te from packed Z (one channel-pair)
__device__ __forceinline__ float2 qmul(float2 a, float2 A, float4 t) {
    float2 Xd = make_float2((a.x + A.x) * 0.5f, (a.y - A.y) * 0.5f);
    float2 Xe = make_float2((a.y + A.y) * 0.5f, (A.x - a.x) * 0.5f);
    float2 A0 = cmul(Xd, make_float2(t.x, t.y));
    float2 B0 = cmul(Xe, make_float2(t.z, t.w));
    return make_float2(A0.x - B0.y, A0.y + B0.x);
}

// ---------------- T precompute: 256 blocks x 1024 thr (verified R9) -------------
__global__ __launch_bounds__(NTHR, 4) void tsep_k(
    const float* __restrict__ T, float4* __restrict__ Tsep)
{
    extern __shared__ float2 S[];
    const int tid = threadIdx.x;
    const int c = blockIdx.x;              // pair [0,256)
    const float* tp = T + (c << 1);

    {
        float2 a0 = *(const float2*)(tp + (size_t)(tid       ) * 512);
        float2 a1 = *(const float2*)(tp + (size_t)(tid + 1024) * 512);
        float2 a2 = *(const float2*)(tp + (size_t)(tid + 2048) * 512);
        float2 a3 = *(const float2*)(tp + (size_t)(tid + 3072) * 512);
        float2 a4 = *(const float2*)(tp + (size_t)(tid + 4096) * 512);
        float2 a5 = *(const float2*)(tp + (size_t)(tid + 5120) * 512);
        float2 a6 = *(const float2*)(tp + (size_t)(tid + 6144) * 512);
        float2 a7 = *(const float2*)(tp + (size_t)(tid + 7168) * 512);
        float sn, cs;
        __sincosf(-TWO_PI * (float)tid / 8192.0f, &sn, &cs);
        float2 w1 = make_float2(cs, sn);
        WCHAIN(w1, w2,w3,w4,w5,w6,w7);
        dft8_fwd(a0,a1,a2,a3,a4,a5,a6,a7);
        S[PAD(tid)]        = a0;
        S[PAD(tid + 1024)] = cmul(a1, w1);
        S[PAD(tid + 2048)] = cmul(a2, w2);
        S[PAD(tid + 3072)] = cmul(a3, w3);
        S[PAD(tid + 4096)] = cmul(a4, w4);
        S[PAD(tid + 5120)] = cmul(a5, w5);
        S[PAD(tid + 6144)] = cmul(a6, w6);
        S[PAD(tid + 7168)] = cmul(a7, w7);
    }
    __syncthreads();
    {
        const int lqs[3] = {7, 4, 1};
        #pragma unroll
        for (int si = 0; si < 3; ++si) {
            const int LQ = lqs[si];
            const int q = 1 << LQ;
            const int m = tid & (q - 1);
            const int B = ((tid >> LQ) << (LQ + 3)) + m;
            const int i0=PAD(B),i1=PAD(B+q),i2=PAD(B+2*q),i3=PAD(B+3*q),
                      i4=PAD(B+4*q),i5=PAD(B+5*q),i6=PAD(B+6*q),i7=PAD(B+7*q);
            float sn, cs;
            __sincosf(-TWO_PI * (float)m / (float)(q << 3), &sn, &cs);
            float2 w1 = make_float2(cs, sn);
            WCHAIN(w1, w2,w3,w4,w5,w6,w7);
            float2 a0=S[i0],a1=S[i1],a2=S[i2],a3=S[i3],a4=S[i4],a5=S[i5],a6=S[i6],a7=S[i7];
            dft8_fwd(a0,a1,a2,a3,a4,a5,a6,a7);
            S[i0]=a0;           S[i1]=cmul(a1,w1); S[i2]=cmul(a2,w2); S[i3]=cmul(a3,w3);
            S[i4]=cmul(a4,w4);  S[i5]=cmul(a5,w5); S[i6]=cmul(a6,w6); S[i7]=cmul(a7,w7);
            __syncthreads();
        }
    }

    const float sc = 0.5f / (float)NFFT;
    float4* tb = Tsep + (size_t)c * NFFT;
    #pragma unroll
    for (int it = 0; it < 4; ++it) {
        int u = tid + (it << 10);
        int K = rev8_12(u);
        int v = rev8_12((4096 - K) & 4095);
        float2 V0 = S[PAD(2*u)], V1 = S[PAD(2*u + 1)];
        float2 Za = cadd(V0, V1), Zb = csub(V0, V1);
        float2 Zc, Zd;
        if (u == 0) { Zc = Zb; Zd = Za; }
        else {
            float2 U0 = S[PAD(2*v)], U1 = S[PAD(2*v + 1)];
            Zc = cadd(U0, U1); Zd = csub(U0, U1);
        }
        tb[2*u]     = make_float4((Za.x + Zd.x) * sc, (Za.y - Zd.y) * sc,
                                  (Za.y + Zd.y) * sc, (Zd.x - Za.x) * sc);
        tb[2*u + 1] = make_float4((Zb.x + Zc.x) * sc, (Zb.y - Zc.y) * sc,
                                  (Zb.y + Zc.y) * sc, (Zc.x - Zb.x) * sc);
    }
}

// ---------------- main conv: 512 blocks x 1024 thr, Tsep reg-prefetch ----------
__global__ __launch_bounds__(NTHR, 2) void fftconv13(
    const float* __restrict__ X, const float4* __restrict__ Tsep,
    float* __restrict__ O)
{
    extern __shared__ float4 S4[];
    const int tid = threadIdx.x;

    // R5/R9 XCD swizzle
    int h = blockIdx.x;                    // [0,512)
    int xcd = h & 7, sl = h >> 3;
    int lbid = ((sl >> 2) << 5) | (xcd << 2) | (sl & 3);
    const int b = lbid >> 7;
    const int g = lbid & 127;
    const float* xp = X + (size_t)b * 4096 * 512 + (g << 2);

    float4 l0 = *(const float4*)(xp + (size_t)(tid       ) * 512);
    float4 l1 = *(const float4*)(xp + (size_t)(tid + 1024) * 512);
    float4 l2 = *(const float4*)(xp + (size_t)(tid + 2048) * 512);
    float4 l3 = *(const float4*)(xp + (size_t)(tid + 3072) * 512);

    // ---- Tsep register prefetch: issued now, consumed after the fwd stages ----
    const float4* tb0 = Tsep + (size_t)(2*g) * NFFT;
    const float4* tb1 = Tsep + (size_t)(2*g + 1) * NFFT;
    float4 tv[16];
    #pragma unroll
    for (int it = 0; it < 4; ++it) {
        int u = tid + (it << 10);
        tv[4*it + 0] = tb0[2*u];
        tv[4*it + 1] = tb0[2*u + 1];
        tv[4*it + 2] = tb1[2*u];
        tv[4*it + 3] = tb1[2*u + 1];
    }

    {
        float sn, cs;
        __sincosf(-TWO_PI * (float)tid / 8192.0f, &sn, &cs);
        float2 w1 = make_float2(cs, sn);
        WCHAIN(w1, w2,w3,w4,w5,w6,w7);
        xstage1_4(l0, l1, l2, l3, S4, tid, w1,w2,w3,w4,w5,w6,w7);
    }
    __syncthreads();
    fwd_stage4<7>(S4, tid); __syncthreads();
    fwd_stage4<4>(S4, tid); __syncthreads();
    fwd_stage4<1>(S4, tid); __syncthreads();

    // ---- sep from registers (fwd-r2 fold + conj-sym + Tmul + inv-r2 fold) ----
    {
        float4 Wr[8];
        #pragma unroll
        for (int it = 0; it < 4; ++it) {
            int u = tid + (it << 10);
            int K = rev8_12(u);
            int v = rev8_12((4096 - K) & 4095);
            float4 V0 = S4[PAD(2*u)], V1 = S4[PAD(2*u + 1)];
            float4 Za = cadd4(V0, V1), Zb = csub4(V0, V1);
            float4 Zc, Zd;
            if (u == 0) { Zc = Zb; Zd = Za; }
            else {
                float4 U0 = S4[PAD(2*v)], U1 = S4[PAD(2*v + 1)];
                Zc = cadd4(U0, U1); Zd = csub4(U0, U1);
            }
            float2 Q0a = qmul(make_float2(Za.x,Za.y), make_float2(Zd.x,Zd.y), tv[4*it + 0]);
            float2 Q1a = qmul(make_float2(Zb.x,Zb.y), make_float2(Zc.x,Zc.y), tv[4*it + 1]);
            float2 Q0b = qmul(make_float2(Za.z,Za.w), make_float2(Zd.z,Zd.w), tv[4*it + 2]);
            float2 Q1b = qmul(make_float2(Zb.z,Zb.w), make_float2(Zc.z,Zc.w), tv[4*it + 3]);
            Wr[2*it]     = make_float4(Q0a.x+Q1a.x, Q0a.y+Q1a.y, Q0b.x+Q1b.x, Q0b.y+Q1b.y);
            Wr[2*it + 1] = make_float4(Q0a.x-Q1a.x, Q0a.y-Q1a.y, Q0b.x-Q1b.x, Q0b.y-Q1b.y);
        }
        __syncthreads();
        #pragma unroll
        for (int it = 0; it < 4; ++it) {
            int u = tid + (it << 10);
            S4[PAD(2*u)]     = Wr[2*it];
            S4[PAD(2*u + 1)] = Wr[2*it + 1];
        }
    }
    __syncthreads();

    inv_stage4<1>(S4, tid); __syncthreads();
    inv_stage4<4>(S4, tid); __syncthreads();
    inv_stage4<7>(S4, tid); __syncthreads();

    {
        float sn, cs;
        __sincosf(TWO_PI * (float)tid / 8192.0f, &sn, &cs);
        float2 w1 = make_float2(cs, sn);
        WCHAIN(w1, w2,w3,w4,w5,w6,w7);
        float4 r0, r1, r2, r3;
        inv_final4(S4, tid, w1,w2,w3,w4,w5,w6,w7, r0, r1, r2, r3);
        float* op = O + (size_t)b * 4096 * 512 + (g << 2);
        *(float4*)(op + (size_t)(tid       ) * 512) = r0;
        *(float4*)(op + (size_t)(tid + 1024) * 512) = r1;
        *(float4*)(op + (size_t)(tid + 2048) * 512) = r2;
        *(float4*)(op + (size_t)(tid + 3072) * 512) = r3;
    }
}

extern "C" void kernel_launch(void* const* d_in, const int* in_sizes, int n_in,
                              void* d_out, int out_size, void* d_ws, size_t ws_size,
                              hipStream_t stream)
{
    const float* x = (const float*)d_in[0];   // (4, 4096, 512)
    const float* t = (const float*)d_in[1];   // (8192, 512)
    float* out = (float*)d_out;               // (4, 4096, 512)
    float4* tsep = (float4*)d_ws;             // 256*8192*16 B = 32 MB

    const int lds_t = (int)(LDS_ELEMS * sizeof(float2));   // 69632
    const int lds_c = (int)(LDS_ELEMS * sizeof(float4));   // 139264
    (void)hipFuncSetAttribute((const void*)tsep_k,
                              hipFuncAttributeMaxDynamicSharedMemorySize, lds_t);
    (void)hipFuncSetAttribute((const void*)fftconv13,
                              hipFuncAttributeMaxDynamicSharedMemorySize, lds_c);

    tsep_k<<<256, NTHR, lds_t, stream>>>(t, tsep);
    fftconv13<<<512, NTHR, lds_c, stream>>>(x, tsep, out);
}

// Round 14
// 82.905 us; speedup vs baseline: 1.5377x; 1.5377x over previous
//
#include <hip/hip_runtime.h>
#include <math.h>

// Round 14: R12 conv (verbatim, verified 66us) + fast e/o tsep in R12 layout.
//   tsep_eo: Z[2m]=FFT4096(t_j+t_{j+4096})[m]; Z[2m+1]=FFT4096((t_j-t_{j+4096})e^{-2pi i j/8192})[m].
//     4096 = 8^4 -> 4 radix-8 stages; q512->q64 needs a barrier, q64->q8 and
//     q8->q1 are wave-local (producers within consumer's wave - verified R11).
//     Tail writes R12's table: tb[2u]=sep(Z[K],Z[8192-K]), tb[2u+1]=sep(Z[K+4096],Z[4096-K]),
//     K=rev8_12(u); parity of K picks Ze/Zo (wave-uniform, bit9 of tid).
//   fftconv14 == R12's fftconv12: float4-fused LDS slots, 512 blocks x 1024 thr.

#define NFFT 8192
#define NTHR 1024
#define PAD(i) ((i) + ((i) >> 4))
#define LDS_ELEMS (NFFT + (NFFT >> 4))          // 8704 slots (conv float4 buffer)
#define BUF2 (4096 + 256)                        // 4352 float2 per e/o buffer
#define TWO_PI 6.28318530717958647692f
#define RSQRT2 0.70710678118654752440f
#define WFENCE() asm volatile("" ::: "memory")

// ---------------- float2 complex ----------------
__device__ __forceinline__ float2 cadd(float2 a, float2 b){ return make_float2(a.x+b.x, a.y+b.y); }
__device__ __forceinline__ float2 csub(float2 a, float2 b){ return make_float2(a.x-b.x, a.y-b.y); }
__device__ __forceinline__ float2 cmul(float2 a, float2 b){ return make_float2(a.x*b.x - a.y*b.y, a.x*b.y + a.y*b.x); }
__device__ __forceinline__ float2 mulnegi(float2 a){ return make_float2(a.y, -a.x); }
__device__ __forceinline__ float2 mulposi(float2 a){ return make_float2(-a.y, a.x); }
__device__ __forceinline__ float2 mulw81(float2 z){ return make_float2(RSQRT2*(z.x+z.y), RSQRT2*(z.y-z.x)); }  // e^{-i pi/4}
__device__ __forceinline__ float2 mulw83(float2 z){ return make_float2(RSQRT2*(z.y-z.x), -RSQRT2*(z.x+z.y)); } // e^{-i 3pi/4}
__device__ __forceinline__ float2 mulv81(float2 z){ return make_float2(RSQRT2*(z.x-z.y), RSQRT2*(z.x+z.y)); }  // e^{+i pi/4}
__device__ __forceinline__ float2 mulv83(float2 z){ return make_float2(-RSQRT2*(z.x+z.y), RSQRT2*(z.x-z.y)); } // e^{+i 3pi/4}

// ---------------- float4 = two packed complex, shared twiddle ----------------
__device__ __forceinline__ float4 cadd4(float4 a, float4 b){ return make_float4(a.x+b.x,a.y+b.y,a.z+b.z,a.w+b.w); }
__device__ __forceinline__ float4 csub4(float4 a, float4 b){ return make_float4(a.x-b.x,a.y-b.y,a.z-b.z,a.w-b.w); }
__device__ __forceinline__ float4 cmul4(float4 a, float2 w){
    return make_float4(a.x*w.x - a.y*w.y, a.x*w.y + a.y*w.x,
                       a.z*w.x - a.w*w.y, a.z*w.y + a.w*w.x);
}
__device__ __forceinline__ float4 mulnegi4(float4 a){ return make_float4(a.y,-a.x, a.w,-a.z); }
__device__ __forceinline__ float4 mulposi4(float4 a){ return make_float4(-a.y,a.x, -a.w,a.z); }
__device__ __forceinline__ float4 mulw81_4(float4 z){
    return make_float4(RSQRT2*(z.x+z.y), RSQRT2*(z.y-z.x), RSQRT2*(z.z+z.w), RSQRT2*(z.w-z.z)); }
__device__ __forceinline__ float4 mulw83_4(float4 z){
    return make_float4(RSQRT2*(z.y-z.x), -RSQRT2*(z.x+z.y), RSQRT2*(z.w-z.z), -RSQRT2*(z.z+z.w)); }
__device__ __forceinline__ float4 mulv81_4(float4 z){
    return make_float4(RSQRT2*(z.x-z.y), RSQRT2*(z.x+z.y), RSQRT2*(z.z-z.w), RSQRT2*(z.z+z.w)); }
__device__ __forceinline__ float4 mulv83_4(float4 z){
    return make_float4(-RSQRT2*(z.x+z.y), RSQRT2*(z.x-z.y), -RSQRT2*(z.z+z.w), RSQRT2*(z.z-z.w)); }

__device__ __forceinline__ int rev8_12(int u) {   // 4-octal-digit reversal, involution
    return ((u & 7) << 9) | (((u >> 3) & 7) << 6) | (((u >> 6) & 7) << 3) | ((u >> 9) & 7);
}

#define WCHAIN(w1, w2,w3,w4,w5,w6,w7) \
    float2 w2 = cmul(w1,w1), w3 = cmul(w2,w1), w4 = cmul(w2,w2), \
           w5 = cmul(w4,w1), w6 = cmul(w4,w2), w7 = cmul(w4,w3)

// ---------------- float2 radix-8 cores (tsep) ----------------
__device__ __forceinline__ void dft8_fwd(float2& a0, float2& a1, float2& a2, float2& a3,
                                         float2& a4, float2& a5, float2& a6, float2& a7) {
    float2 s02 = cadd(a0,a4), d02 = csub(a0,a4), s13 = cadd(a2,a6), d13 = csub(a2,a6);
    float2 E0 = cadd(s02,s13), E2 = csub(s02,s13);
    float2 E1 = cadd(d02, mulnegi(d13)), E3 = csub(d02, mulnegi(d13));
    float2 t02 = cadd(a1,a5), u02 = csub(a1,a5), t13 = cadd(a3,a7), u13 = csub(a3,a7);
    float2 O0 = cadd(t02,t13), O2 = csub(t02,t13);
    float2 O1 = cadd(u02, mulnegi(u13)), O3 = csub(u02, mulnegi(u13));
    float2 W1 = mulw81(O1), W2 = mulnegi(O2), W3 = mulw83(O3);
    a0 = cadd(E0,O0); a4 = csub(E0,O0);
    a1 = cadd(E1,W1); a5 = csub(E1,W1);
    a2 = cadd(E2,W2); a6 = csub(E2,W2);
    a3 = cadd(E3,W3); a7 = csub(E3,W3);
}

__device__ __forceinline__ void fwd_one(float2* __restrict__ S,
    int i0,int i1,int i2,int i3,int i4,int i5,int i6,int i7,
    float2 w1,float2 w2,float2 w3,float2 w4,float2 w5,float2 w6,float2 w7) {
    float2 a0=S[i0],a1=S[i1],a2=S[i2],a3=S[i3],a4=S[i4],a5=S[i5],a6=S[i6],a7=S[i7];
    dft8_fwd(a0,a1,a2,a3,a4,a5,a6,a7);
    S[i0]=a0;           S[i1]=cmul(a1,w1); S[i2]=cmul(a2,w2); S[i3]=cmul(a3,w3);
    S[i4]=cmul(a4,w4);  S[i5]=cmul(a5,w5); S[i6]=cmul(a6,w6); S[i7]=cmul(a7,w7);
}

template<int LQ>
__device__ __forceinline__ void fwd_single(float2* __restrict__ S, int p) {
    const int q = 1 << LQ;
    const int m = p & (q - 1);
    const int B = ((p >> LQ) << (LQ + 3)) + m;
    const int i0=PAD(B),i1=PAD(B+q),i2=PAD(B+2*q),i3=PAD(B+3*q),
              i4=PAD(B+4*q),i5=PAD(B+5*q),i6=PAD(B+6*q),i7=PAD(B+7*q);
    float sn, cs;
    __sincosf(-TWO_PI * (float)m / (float)(q << 3), &sn, &cs);
    float2 w1 = make_float2(cs, sn);
    WCHAIN(w1, w2,w3,w4,w5,w6,w7);
    fwd_one(S,i0,i1,i2,i3,i4,i5,i6,i7,w1,w2,w3,w4,w5,w6,w7);
}

__device__ __forceinline__ void plain_one_fwd(float2* __restrict__ S, int p) {   // q=1
    const int base = p << 3;
    const int i0=PAD(base),i1=PAD(base+1),i2=PAD(base+2),i3=PAD(base+3),
              i4=PAD(base+4),i5=PAD(base+5),i6=PAD(base+6),i7=PAD(base+7);
    float2 a0=S[i0],a1=S[i1],a2=S[i2],a3=S[i3],a4=S[i4],a5=S[i5],a6=S[i6],a7=S[i7];
    dft8_fwd(a0,a1,a2,a3,a4,a5,a6,a7);
    S[i0]=a0; S[i1]=a1; S[i2]=a2; S[i3]=a3; S[i4]=a4; S[i5]=a5; S[i6]=a6; S[i7]=a7;
}

// ---------------- float4 radix-8 cores (conv, verbatim R12) ----------------
__device__ __forceinline__ void dft8_fwd4(float4& a0, float4& a1, float4& a2, float4& a3,
                                          float4& a4, float4& a5, float4& a6, float4& a7) {
    float4 s02 = cadd4(a0,a4), d02 = csub4(a0,a4), s13 = cadd4(a2,a6), d13 = csub4(a2,a6);
    float4 E0 = cadd4(s02,s13), E2 = csub4(s02,s13);
    float4 E1 = cadd4(d02, mulnegi4(d13)), E3 = csub4(d02, mulnegi4(d13));
    float4 t02 = cadd4(a1,a5), u02 = csub4(a1,a5), t13 = cadd4(a3,a7), u13 = csub4(a3,a7);
    float4 O0 = cadd4(t02,t13), O2 = csub4(t02,t13);
    float4 O1 = cadd4(u02, mulnegi4(u13)), O3 = csub4(u02, mulnegi4(u13));
    float4 W1 = mulw81_4(O1), W2 = mulnegi4(O2), W3 = mulw83_4(O3);
    a0 = cadd4(E0,O0); a4 = csub4(E0,O0);
    a1 = cadd4(E1,W1); a5 = csub4(E1,W1);
    a2 = cadd4(E2,W2); a6 = csub4(E2,W2);
    a3 = cadd4(E3,W3); a7 = csub4(E3,W3);
}

__device__ __forceinline__ void dft8_inv4(float4& a0, float4& a1, float4& a2, float4& a3,
                                          float4& a4, float4& a5, float4& a6, float4& a7) {
    float4 s02 = cadd4(a0,a4), d02 = csub4(a0,a4), s13 = cadd4(a2,a6), d13 = csub4(a2,a6);
    float4 P0 = cadd4(s02,s13), P2 = csub4(s02,s13);
    float4 P1 = cadd4(d02, mulposi4(d13)), P3 = csub4(d02, mulposi4(d13));
    float4 t02 = cadd4(a1,a5), u02 = csub4(a1,a5), t13 = cadd4(a3,a7), u13 = csub4(a3,a7);
    float4 Q0 = cadd4(t02,t13), Q2 = csub4(t02,t13);
    float4 Q1 = cadd4(u02, mulposi4(u13)), Q3 = csub4(u02, mulposi4(u13));
    float4 W1 = mulv81_4(Q1), W2 = mulposi4(Q2), W3 = mulv83_4(Q3);
    a0 = cadd4(P0,Q0); a4 = csub4(P0,Q0);
    a1 = cadd4(P1,W1); a5 = csub4(P1,W1);
    a2 = cadd4(P2,W2); a6 = csub4(P2,W2);
    a3 = cadd4(P3,W3); a7 = csub4(P3,W3);
}

template<int LQ>
__device__ __forceinline__ void fwd_stage4(float4* __restrict__ S, int tid) {
    const int q = 1 << LQ;
    const int m = tid & (q - 1);
    const int B = ((tid >> LQ) << (LQ + 3)) + m;
    const int i0=PAD(B),i1=PAD(B+q),i2=PAD(B+2*q),i3=PAD(B+3*q),
              i4=PAD(B+4*q),i5=PAD(B+5*q),i6=PAD(B+6*q),i7=PAD(B+7*q);
    float sn, cs;
    __sincosf(-TWO_PI * (float)m / (float)(q << 3), &sn, &cs);
    float2 w1 = make_float2(cs, sn);
    WCHAIN(w1, w2,w3,w4,w5,w6,w7);
    float4 a0=S[i0],a1=S[i1],a2=S[i2],a3=S[i3],a4=S[i4],a5=S[i5],a6=S[i6],a7=S[i7];
    dft8_fwd4(a0,a1,a2,a3,a4,a5,a6,a7);
    S[i0]=a0;            S[i1]=cmul4(a1,w1); S[i2]=cmul4(a2,w2); S[i3]=cmul4(a3,w3);
    S[i4]=cmul4(a4,w4);  S[i5]=cmul4(a5,w5); S[i6]=cmul4(a6,w6); S[i7]=cmul4(a7,w7);
}

template<int LQ>
__device__ __forceinline__ void inv_stage4(float4* __restrict__ S, int tid) {
    const int q = 1 << LQ;
    const int m = tid & (q - 1);
    const int B = ((tid >> LQ) << (LQ + 3)) + m;
    const int i0=PAD(B),i1=PAD(B+q),i2=PAD(B+2*q),i3=PAD(B+3*q),
              i4=PAD(B+4*q),i5=PAD(B+5*q),i6=PAD(B+6*q),i7=PAD(B+7*q);
    float sn, cs;
    __sincosf(TWO_PI * (float)m / (float)(q << 3), &sn, &cs);
    float2 w1 = make_float2(cs, sn);
    WCHAIN(w1, w2,w3,w4,w5,w6,w7);
    float4 a0 = S[i0];
    float4 a1=cmul4(S[i1],w1), a2=cmul4(S[i2],w2), a3=cmul4(S[i3],w3), a4=cmul4(S[i4],w4),
           a5=cmul4(S[i5],w5), a6=cmul4(S[i6],w6), a7=cmul4(S[i7],w7);
    dft8_inv4(a0,a1,a2,a3,a4,a5,a6,a7);
    S[i0]=a0; S[i1]=a1; S[i2]=a2; S[i3]=a3; S[i4]=a4; S[i5]=a5; S[i6]=a6; S[i7]=a7;
}

__device__ __forceinline__ void xstage1_4(float4 a0, float4 a1, float4 a2, float4 a3,
    float4* __restrict__ S, int tid,
    float2 w1,float2 w2,float2 w3,float2 w4,float2 w5,float2 w6,float2 w7) {
    float4 s02 = cadd4(a0,a2), d02 = csub4(a0,a2), s13 = cadd4(a1,a3), d13 = csub4(a1,a3);
    float4 F0 = cadd4(s02,s13), F2 = csub4(s02,s13);
    float4 F1 = cadd4(d02, mulnegi4(d13)), F3 = csub4(d02, mulnegi4(d13));
    float4 g1 = mulw81_4(a1), g2 = mulnegi4(a2), g3 = mulw83_4(a3);
    float4 gs02 = cadd4(a0,g2), gd02 = csub4(a0,g2), gs13 = cadd4(g1,g3), gd13 = csub4(g1,g3);
    float4 G0 = cadd4(gs02,gs13), G2 = csub4(gs02,gs13);
    float4 G1 = cadd4(gd02, mulnegi4(gd13)), G3 = csub4(gd02, mulnegi4(gd13));
    S[PAD(tid)]        = F0;
    S[PAD(tid + 1024)] = cmul4(G0, w1);
    S[PAD(tid + 2048)] = cmul4(F1, w2);
    S[PAD(tid + 3072)] = cmul4(G1, w3);
    S[PAD(tid + 4096)] = cmul4(F2, w4);
    S[PAD(tid + 5120)] = cmul4(G2, w5);
    S[PAD(tid + 6144)] = cmul4(F3, w6);
    S[PAD(tid + 7168)] = cmul4(G3, w7);
}

__device__ __forceinline__ void inv_final4(const float4* __restrict__ S, int tid,
    float2 w1,float2 w2,float2 w3,float2 w4,float2 w5,float2 w6,float2 w7,
    float4& r0, float4& r1, float4& r2, float4& r3) {
    float4 z0 = S[PAD(tid)];
    float4 z1 = cmul4(S[PAD(tid + 1024)], w1);
    float4 z2 = cmul4(S[PAD(tid + 2048)], w2);
    float4 z3 = cmul4(S[PAD(tid + 3072)], w3);
    float4 z4 = cmul4(S[PAD(tid + 4096)], w4);
    float4 z5 = cmul4(S[PAD(tid + 5120)], w5);
    float4 z6 = cmul4(S[PAD(tid + 6144)], w6);
    float4 z7 = cmul4(S[PAD(tid + 7168)], w7);
    float4 s02 = cadd4(z0,z4), d02 = csub4(z0,z4), s13 = cadd4(z2,z6), d13 = csub4(z2,z6);
    float4 P0 = cadd4(s02,s13), P2 = csub4(s02,s13);
    float4 P1 = cadd4(d02, mulposi4(d13)), P3 = csub4(d02, mulposi4(d13));
    float4 t02 = cadd4(z1,z5), u02 = csub4(z1,z5), t13 = cadd4(z3,z7), u13 = csub4(z3,z7);
    float4 Q0 = cadd4(t02,t13), Q2 = csub4(t02,t13);
    float4 Q1 = cadd4(u02, mulposi4(u13)), Q3 = csub4(u02, mulposi4(u13));
    r0 = cadd4(P0, Q0);
    r1 = cadd4(P1, mulv81_4(Q1));
    r2 = cadd4(P2, mulposi4(Q2));
    r3 = cadd4(P3, mulv83_4(Q3));
}

__device__ __forceinline__ float2 qmul(float2 a, float2 A, float4 t) {
    float2 Xd = make_float2((a.x + A.x) * 0.5f, (a.y - A.y) * 0.5f);
    float2 Xe = make_float2((a.y + A.y) * 0.5f, (A.x - a.x) * 0.5f);
    float2 A0 = cmul(Xd, make_float2(t.x, t.y));
    float2 B0 = cmul(Xe, make_float2(t.z, t.w));
    return make_float2(A0.x - B0.y, A0.y + B0.x);
}

__device__ __forceinline__ float4 sep4(float2 Zk, float2 Zn, float sc) {
    return make_float4((Zk.x + Zn.x) * sc, (Zk.y - Zn.y) * sc,
                       (Zk.y + Zn.y) * sc, (Zn.x - Zk.x) * sc);
}

// ---------------- T precompute: e/o split, R12-layout tail ----------------
__global__ __launch_bounds__(NTHR, 2) void tsep_eo(
    const float* __restrict__ T, float4* __restrict__ Tsep)
{
    extern __shared__ float2 L[];
    float2* Te = L;
    float2* To = L + BUF2;
    const int tid = threadIdx.x;

    int h = blockIdx.x;                        // [0,256)
    const int c = ((h & 7) << 5) | (h >> 3);
    const float* tp = T + (c << 1);

    // fold + modulate: Te[r]=t[r]+t[r+4096]; To[r]=(t[r]-t[r+4096])*e^{-2pi i r/8192}
    {
        float sn, cs;
        __sincosf(-TWO_PI * (float)tid / 8192.0f, &sn, &cs);
        float2 m = make_float2(cs, sn);
        const float2 CF4 = make_float2(RSQRT2, -RSQRT2);   // e^{-i pi/4} per 1024-step
        #pragma unroll
        for (int j = 0; j < 4; ++j) {
            int r = tid + (j << 10);
            float2 va = *(const float2*)(tp + (size_t)r * 512);
            float2 vb = *(const float2*)(tp + (size_t)(r + 4096) * 512);
            Te[PAD(r)] = cadd(va, vb);
            To[PAD(r)] = cmul(csub(va, vb), m);
            m = cmul(m, CF4);
        }
    }
    __syncthreads();                                       // B1

    const int p = tid & 511;
    float2* Sb = (tid >> 9) ? To : Te;
    fwd_single<9>(Sb, p);
    __syncthreads();                                       // B2 (q512->q64 spans waves)
    fwd_single<6>(Sb, p);  WFENCE();                       // q64->q8 wave-local
    fwd_single<3>(Sb, p);  WFENCE();                       // q8->q1 wave-local
    plain_one_fwd(Sb, p);
    __syncthreads();                                       // B3

    // tail: write R12's (Td,Te) table. K=rev(u); parity picks buffer (bit9 of tid,
    // wave-uniform). Self-pairing at K=0 / K=4096 falls out of the formulas.
    const float sc = 0.5f / (float)NFFT;
    float4* tb = Tsep + (size_t)c * NFFT;
    #pragma unroll
    for (int it = 0; it < 4; ++it) {
        int u = tid + (it << 10);              // [0,4096)
        int K = rev8_12(u);
        const float2* S = (K & 1) ? To : Te;
        int m1  = K >> 1;
        int mp  = ((8192 - K) & 8191) >> 1;
        int m2  = m1 + 2048;
        int m2p = ((4096 - K) & 8191) >> 1;
        float2 Za = S[PAD(rev8_12(m1))];
        float2 Zd = S[PAD(rev8_12(mp))];
        float2 Zb = S[PAD(rev8_12(m2))];
        float2 Zc = S[PAD(rev8_12(m2p))];
        tb[2*u]     = sep4(Za, Zd, sc);        // freq K with partner 8192-K
        tb[2*u + 1] = sep4(Zb, Zc, sc);        // freq K+4096 with partner 4096-K
    }
}

// ---------------- main conv: verbatim R12 (verified) ----------------
__global__ __launch_bounds__(NTHR, 4) void fftconv14(
    const float* __restrict__ X, const float4* __restrict__ Tsep,
    float* __restrict__ O)
{
    extern __shared__ float4 S4[];
    const int tid = threadIdx.x;

    int h = blockIdx.x;                    // [0,512)
    int xcd = h & 7, sl = h >> 3;
    int lbid = ((sl >> 2) << 5) | (xcd << 2) | (sl & 3);
    const int b = lbid >> 7;
    const int g = lbid & 127;
    const float* xp = X + (size_t)b * 4096 * 512 + (g << 2);

    float4 l0 = *(const float4*)(xp + (size_t)(tid       ) * 512);
    float4 l1 = *(const float4*)(xp + (size_t)(tid + 1024) * 512);
    float4 l2 = *(const float4*)(xp + (size_t)(tid + 2048) * 512);
    float4 l3 = *(const float4*)(xp + (size_t)(tid + 3072) * 512);
    {
        float sn, cs;
        __sincosf(-TWO_PI * (float)tid / 8192.0f, &sn, &cs);
        float2 w1 = make_float2(cs, sn);
        WCHAIN(w1, w2,w3,w4,w5,w6,w7);
        xstage1_4(l0, l1, l2, l3, S4, tid, w1,w2,w3,w4,w5,w6,w7);
    }
    __syncthreads();
    fwd_stage4<7>(S4, tid); __syncthreads();
    fwd_stage4<4>(S4, tid); __syncthreads();
    fwd_stage4<1>(S4, tid); __syncthreads();

    // sep: fwd-r2 fold + conj-sym + Tmul + inv-r2 fold
    {
        const float4* tb0 = Tsep + (size_t)(2*g) * NFFT;
        const float4* tb1 = Tsep + (size_t)(2*g + 1) * NFFT;
        float4 Wr[8];
        #pragma unroll
        for (int it = 0; it < 4; ++it) {
            int u = tid + (it << 10);
            int K = rev8_12(u);
            int v = rev8_12((4096 - K) & 4095);
            float4 V0 = S4[PAD(2*u)], V1 = S4[PAD(2*u + 1)];
            float4 Za = cadd4(V0, V1), Zb = csub4(V0, V1);
            float4 Zc, Zd;
            if (u == 0) { Zc = Zb; Zd = Za; }
            else {
                float4 U0 = S4[PAD(2*v)], U1 = S4[PAD(2*v + 1)];
                Zc = cadd4(U0, U1); Zd = csub4(U0, U1);
            }
            float4 ta0 = tb0[2*u], ta1 = tb0[2*u + 1];
            float4 tc0 = tb1[2*u], tc1 = tb1[2*u + 1];
            float2 Q0a = qmul(make_float2(Za.x,Za.y), make_float2(Zd.x,Zd.y), ta0);
            float2 Q1a = qmul(make_float2(Zb.x,Zb.y), make_float2(Zc.x,Zc.y), ta1);
            float2 Q0b = qmul(make_float2(Za.z,Za.w), make_float2(Zd.z,Zd.w), tc0);
            float2 Q1b = qmul(make_float2(Zb.z,Zb.w), make_float2(Zc.z,Zc.w), tc1);
            Wr[2*it]     = make_float4(Q0a.x+Q1a.x, Q0a.y+Q1a.y, Q0b.x+Q1b.x, Q0b.y+Q1b.y);
            Wr[2*it + 1] = make_float4(Q0a.x-Q1a.x, Q0a.y-Q1a.y, Q0b.x-Q1b.x, Q0b.y-Q1b.y);
        }
        __syncthreads();
        #pragma unroll
        for (int it = 0; it < 4; ++it) {
            int u = tid + (it << 10);
            S4[PAD(2*u)]     = Wr[2*it];
            S4[PAD(2*u + 1)] = Wr[2*it + 1];
        }
    }
    __syncthreads();

    inv_stage4<1>(S4, tid); __syncthreads();
    inv_stage4<4>(S4, tid); __syncthreads();
    inv_stage4<7>(S4, tid); __syncthreads();

    {
        float sn, cs;
        __sincosf(TWO_PI * (float)tid / 8192.0f, &sn, &cs);
        float2 w1 = make_float2(cs, sn);
        WCHAIN(w1, w2,w3,w4,w5,w6,w7);
        float4 r0, r1, r2, r3;
        inv_final4(S4, tid, w1,w2,w3,w4,w5,w6,w7, r0, r1, r2, r3);
        float* op = O + (size_t)b * 4096 * 512 + (g << 2);
        *(float4*)(op + (size_t)(tid       ) * 512) = r0;
        *(float4*)(op + (size_t)(tid + 1024) * 512) = r1;
        *(float4*)(op + (size_t)(tid + 2048) * 512) = r2;
        *(float4*)(op + (size_t)(tid + 3072) * 512) = r3;
    }
}

extern "C" void kernel_launch(void* const* d_in, const int* in_sizes, int n_in,
                              void* d_out, int out_size, void* d_ws, size_t ws_size,
                              hipStream_t stream)
{
    const float* x = (const float*)d_in[0];   // (4, 4096, 512)
    const float* t = (const float*)d_in[1];   // (8192, 512)
    float* out = (float*)d_out;               // (4, 4096, 512)
    float4* tsep = (float4*)d_ws;             // 256*8192*16 B = 32 MB

    const int lds_t = (int)(2 * BUF2 * sizeof(float2));    // 69632
    const int lds_c = (int)(LDS_ELEMS * sizeof(float4));   // 139264
    (void)hipFuncSetAttribute((const void*)tsep_eo,
                              hipFuncAttributeMaxDynamicSharedMemorySize, lds_t);
    (void)hipFuncSetAttribute((const void*)fftconv14,
                              hipFuncAttributeMaxDynamicSharedMemorySize, lds_c);

    tsep_eo<<<256, NTHR, lds_t, stream>>>(t, tsep);
    fftconv14<<<512, NTHR, lds_c, stream>>>(x, tsep, out);
}